// Round 16
// baseline (120.138 us; speedup 1.0000x reference)
//
#include <hip/hip_runtime.h>

typedef __attribute__((ext_vector_type(4))) float f32x4;

#define NT 256
#define S 10
#define D 100
#define H 16
#define NITER 5
#define GL 10                // lanes per batch row: exactly 1 s-row per lane
#define GPW 6                // groups per wave (lanes 0..59; 60..63 idle)
#define RPB (4 * GPW)        // 24 batch rows per 256-thread block
#define BS 65536
#define RQ 25                // out-staging row stride in quads (24 + 1 pad)
#define OUTQ 24              // quads per output row (6*16 floats)

// Wave-uniform weight/bias reads straight from global (scalar/constant
// cache path; no LDS tile -> no VGPR promotion balloon -> no spill).
#define WQ(base, d, q) (*(const f32x4*)&(base)[(d) * H + (q) * 4])

__global__ __launch_bounds__(NT, 1)
void attn_greedy_kernel(const float* __restrict__ user_intent,
                        const float* __restrict__ item_corpus,
                        const float* __restrict__ W_proj,
                        const float* __restrict__ b_proj,
                        const float* __restrict__ W_k,
                        const float* __restrict__ b_k,
                        float* __restrict__ out)
{
    __shared__ f32x4 s_out[RPB * RQ];      // 9.6 KB out staging (only LDS)

    const int t = threadIdx.x;
    const int lane = t & 63;
    const int wv = t >> 6;
    const int gl = lane % GL;              // 0..9 == this lane's s-row
    const int grp = lane / GL;             // 0..5 (6 for idle lanes)
    const bool valid = (lane < GL * GPW);  // lanes 60..63 idle (no stores)
    const int rr = valid ? (wv * GPW + grp) : 0;         // row within block
    const size_t b = (size_t)blockIdx.x * RPB + rr;
    const bool brow_ok = valid && (b < BS);
    const size_t bc = (b < BS) ? b : (BS - 1);           // clamp loads only

    // this lane owns s-row gl: ONE live corpus stream (r13 lesson)
    const f32x4* crow = (const f32x4*)item_corpus + bc * (S * D / 4)
                        + gl * (D / 4);

    // biases: uniform -> scalar regs
    f32x4 bp[4], bk[4];
    #pragma unroll
    for (int q = 0; q < 4; ++q) {
        bp[q] = *(const f32x4*)&b_proj[q * 4];
        bk[q] = *(const f32x4*)&b_k[q * 4];
    }

    // user_intent: all group lanes hold the row (same line; broadcast).
    const f32x4* urow = (const f32x4*)user_intent + bc * 4;
    f32x4 usum[4];
    #pragma unroll
    for (int q = 0; q < 4; ++q) {
        usum[q] = urow[q];
        if (gl == 0 && brow_ok) s_out[rr * RQ + q] = usum[q];   // ui[:,0,:]
    }

    // ---- Projection of exactly ONE row, d-ascending (bit-identical).
    f32x4 ic[4];
    {
        f32x4 a0 = bp[0], a1 = bp[1], a2 = bp[2], a3 = bp[3];
        #pragma unroll 5
        for (int i = 0; i < D / 4; ++i) {
            f32x4 c = crow[i];
            #pragma unroll
            for (int dd = 0; dd < 4; ++dd) {
                float a = c[dd];
                const int d = i * 4 + dd;
                a0 += a * WQ(W_proj, d, 0);
                a1 += a * WQ(W_proj, d, 1);
                a2 += a * WQ(W_proj, d, 2);
                a3 += a * WQ(W_proj, d, 3);
            }
        }
        ic[0] = a0; ic[1] = a1; ic[2] = a2; ic[3] = a3;
    }

    const int base = lane - gl;            // first lane of this group

    // ---- Greedy iterations (no divergence in the hot path)
    #pragma unroll 1
    for (int it = 0; it < NITER; ++it) {
        // ic = ic @ Wk + bk for this lane's single row (k ascending)
        {
            f32x4 n0 = bk[0], n1 = bk[1], n2 = bk[2], n3 = bk[3];
            #pragma unroll
            for (int k = 0; k < H; ++k) {
                float a = ic[k >> 2][k & 3];
                n0 += a * WQ(W_k, k, 0);
                n1 += a * WQ(W_k, k, 1);
                n2 += a * WQ(W_k, k, 2);
                n3 += a * WQ(W_k, k, 3);
            }
            ic[0] = n0; ic[1] = n1; ic[2] = n2; ic[3] = n3;
        }

        // src = mean(ui); usum bit-identical within the group
        float cnt = (float)(it + 1);
        f32x4 src[4];
        #pragma unroll
        for (int q = 0; q < 4; ++q) src[q] = usum[q] / cnt;

        // this lane's score (q,c ascending -> same order as all passing rounds)
        float sc = 0.0f;
        #pragma unroll
        for (int q = 0; q < 4; ++q)
            #pragma unroll
            for (int c = 0; c < 4; ++c)
                sc += ic[q][c] * src[q][c];

        // group fold over lanes base..base+9, ascending lane == ascending s:
        // strict > keeps the FIRST max -> exact np.argmax semantics.
        float fbest = __shfl(sc, base & 63);
        int fidx = 0;
        #pragma unroll
        for (int j = 1; j < GL; ++j) {
            float osc = __shfl(sc, (base + j) & 63);
            if (osc > fbest) { fbest = osc; fidx = j; }
        }

        // item_vec: pure broadcast from the owner lane (bit-exact).
        const int owner = (base + fidx) & 63;
        f32x4 iv[4];
        #pragma unroll
        for (int q = 0; q < 4; ++q)
            #pragma unroll
            for (int c = 0; c < 4; ++c)
                iv[q][c] = __shfl(ic[q][c], owner);

        #pragma unroll
        for (int q = 0; q < 4; ++q) {
            usum[q] += iv[q];
            if (gl == 0 && brow_ok) s_out[rr * RQ + (it + 1) * 4 + q] = iv[q];
        }
    }

    // ---- Coalesced output: 24 rows x 24 quads, contiguous per block.
    __syncthreads();
    f32x4* out4 = (f32x4*)out;
    const size_t rbase = (size_t)blockIdx.x * RPB;
    const size_t obase = rbase * OUTQ;
    #pragma unroll
    for (int k = 0; k < 3; ++k) {          // ceil(576/256)
        int j = t + k * NT;
        if (j < RPB * OUTQ) {
            int row = j / OUTQ;
            int q = j - row * OUTQ;
            if (rbase + row < BS)
                out4[obase + j] = s_out[row * RQ + q];
        }
    }
}

extern "C" void kernel_launch(void* const* d_in, const int* in_sizes, int n_in,
                              void* d_out, int out_size, void* d_ws, size_t ws_size,
                              hipStream_t stream) {
    const float* user_intent = (const float*)d_in[0];
    const float* item_corpus = (const float*)d_in[1];
    const float* W_proj      = (const float*)d_in[2];
    const float* b_proj      = (const float*)d_in[3];
    const float* W_k         = (const float*)d_in[4];
    const float* b_k         = (const float*)d_in[5];
    float* out = (float*)d_out;

    const int nblocks = (BS + RPB - 1) / RPB;   // 2731
    hipLaunchKernelGGL(attn_greedy_kernel,
                       dim3(nblocks), dim3(NT), 0, stream,
                       user_intent, item_corpus, W_proj, b_proj, W_k, b_k, out);
}